// Round 14
// baseline (121.246 us; speedup 1.0000x reference)
//
#include <hip/hip_runtime.h>
#include <cstdint>
#include <cstddef>

// Problem constants (fixed by the reference: N=4096, D=512)
constexpr int N_ROWS = 4096;
constexpr int D      = 512;   // bytes per fp8 row == elements
constexpr int M      = 8192;  // 2N
constexpr int NTILE  = 64;    // M / 128
constexpr int NBLK   = NTILE * (NTILE + 1) / 2;   // 2080 upper-tri tile pairs

using f32x4 = __attribute__((ext_vector_type(4))) float;
using i32x4 = __attribute__((ext_vector_type(4))) int;
using i32x8 = __attribute__((ext_vector_type(8))) int;

// 16B async global->LDS copy. LDS dest is wave-uniform base + lane*16.
#define ASYNC_CP16(gsrc, ldst)                                                      \
    __builtin_amdgcn_global_load_lds(                                               \
        (const __attribute__((address_space(1))) unsigned int*)(gsrc),              \
        (__attribute__((address_space(3))) unsigned int*)(ldst), 16, 0, 0)

// sum of squares of the 4 fp8 e4m3 bytes in `pk` (selector must be literal)
#define SS_FP8(pk, accum)                                                           \
    do {                                                                            \
        float f0 = __builtin_amdgcn_cvt_f32_fp8((pk), 0);                           \
        float f1 = __builtin_amdgcn_cvt_f32_fp8((pk), 1);                           \
        float f2 = __builtin_amdgcn_cvt_f32_fp8((pk), 2);                           \
        float f3 = __builtin_amdgcn_cvt_f32_fp8((pk), 3);                           \
        (accum) += f0 * f0 + f1 * f1 + f2 * f2 + f3 * f3;                           \
    } while (0)

// ---------------------------------------------------------------------------
// Kernel 1: fused normalize + fp8-quantize + positive-pair logits.
// One wave handles PAIR k: row k (emb_i) and row k+N (emb_j).
// Also zeroes out[0] (rowfin atomically accumulates the loss into it).
// ---------------------------------------------------------------------------
__global__ __launch_bounds__(256) void normpos_kernel(
    const float* __restrict__ emb_i, const float* __restrict__ emb_j,
    uint8_t* __restrict__ zb, float* __restrict__ diagss,
    float* __restrict__ pos, float* __restrict__ out)
{
    const int wave = threadIdx.x >> 6, lane = threadIdx.x & 63;
    const int k = blockIdx.x * 4 + wave;
    if (blockIdx.x == 0 && threadIdx.x == 0) out[0] = 0.0f;

    const float4* a = (const float4*)(emb_i + (size_t)k * D);
    const float4* b = (const float4*)(emb_j + (size_t)k * D);
    float4 a0 = a[lane * 2], a1 = a[lane * 2 + 1];
    float4 b0 = b[lane * 2], b1 = b[lane * 2 + 1];

    float ssi = a0.x*a0.x + a0.y*a0.y + a0.z*a0.z + a0.w*a0.w
              + a1.x*a1.x + a1.y*a1.y + a1.z*a1.z + a1.w*a1.w;
    float ssj = b0.x*b0.x + b0.y*b0.y + b0.z*b0.z + b0.w*b0.w
              + b1.x*b1.x + b1.y*b1.y + b1.z*b1.z + b1.w*b1.w;
    float dp  = a0.x*b0.x + a0.y*b0.y + a0.z*b0.z + a0.w*b0.w
              + a1.x*b1.x + a1.y*b1.y + a1.z*b1.z + a1.w*b1.w;
    #pragma unroll
    for (int off = 32; off; off >>= 1) {
        ssi += __shfl_xor(ssi, off, 64);
        ssj += __shfl_xor(ssj, off, 64);
        dp  += __shfl_xor(dp,  off, 64);
    }
    const float invi = rsqrtf(ssi), invj = rsqrtf(ssj);

    const float zi[8] = {a0.x*invi, a0.y*invi, a0.z*invi, a0.w*invi,
                         a1.x*invi, a1.y*invi, a1.z*invi, a1.w*invi};
    const float zj[8] = {b0.x*invj, b0.y*invj, b0.z*invj, b0.w*invj,
                         b1.x*invj, b1.y*invj, b1.z*invj, b1.w*invj};

    // quantize to fp8 e4m3 (HW RNE + subnormals), dequant for diag sumsq
    int pi0 = __builtin_amdgcn_cvt_pk_fp8_f32(zi[0], zi[1], 0, false);
    pi0     = __builtin_amdgcn_cvt_pk_fp8_f32(zi[2], zi[3], pi0, true);
    int pi1 = __builtin_amdgcn_cvt_pk_fp8_f32(zi[4], zi[5], 0, false);
    pi1     = __builtin_amdgcn_cvt_pk_fp8_f32(zi[6], zi[7], pi1, true);
    int pj0 = __builtin_amdgcn_cvt_pk_fp8_f32(zj[0], zj[1], 0, false);
    pj0     = __builtin_amdgcn_cvt_pk_fp8_f32(zj[2], zj[3], pj0, true);
    int pj1 = __builtin_amdgcn_cvt_pk_fp8_f32(zj[4], zj[5], 0, false);
    pj1     = __builtin_amdgcn_cvt_pk_fp8_f32(zj[6], zj[7], pj1, true);

    float dssi = 0.f, dssj = 0.f;
    SS_FP8(pi0, dssi);
    SS_FP8(pi1, dssi);
    SS_FP8(pj0, dssj);
    SS_FP8(pj1, dssj);

    const unsigned long long vi =
        ((unsigned long long)(unsigned)pi1 << 32) | (unsigned)pi0;
    const unsigned long long vj =
        ((unsigned long long)(unsigned)pj1 << 32) | (unsigned)pj0;
    *(unsigned long long*)(zb + (size_t)k * D + lane * 8)            = vi;
    *(unsigned long long*)(zb + (size_t)(k + N_ROWS) * D + lane * 8) = vj;

    #pragma unroll
    for (int off = 32; off; off >>= 1) {
        dssi += __shfl_xor(dssi, off, 64);
        dssj += __shfl_xor(dssj, off, 64);
    }
    if (lane == 0) {
        diagss[k]          = dssi;
        diagss[k + N_ROWS] = dssj;
        pos[k]             = 2.0f * dp * invi * invj;
    }
}

// ---------------------------------------------------------------------------
// Kernel 2: symmetric fused sim-GEMM, MX-scaled fp8 K=128 (unit scales) +
// exp + row/col partials. FULL-K LDS: both 128x512 fp8 tiles (128 KB dynamic
// LDS) staged ONCE, ONE barrier, then 4x8 scale-MFMAs per wave with zero
// further syncs. Rationale: rounds 6-13 pinned simgemm at ~44 us because
// __syncthreads' vmcnt(0) drains even the just-issued prefetch — the
// barriered K-loop can't overlap (m97-plateau mechanism). Removing the
// K-loop leaves a single staging drain per block.
// 512 threads = 8 waves of 32x64 (round-13 no-spill register shape:
// acc 32 + af 16 + bg 32 << 256 VGPR at 2 waves/SIMD). 1 block/CU.
// LDS rows 512 B, 16B-chunk swizzle p = c ^ (row&7): fragment ds_read_b128
// is 2-way on banks (free, m136); staging CP16s read contiguous 1 KB spans.
// ZERO global atomics in the hot path; wave partials combined via LDS,
// stored exactly once (rows -> partials[bi][bj], sym cols -> partials[bj][bi]).
// ---------------------------------------------------------------------------
__global__ __launch_bounds__(512, 2) void simgemm_kernel(
    const uint8_t* __restrict__ zb, float* __restrict__ partials)
{
    extern __shared__ uint8_t lds[];
    uint8_t* As = lds;                                  // 64 KB [128][512]
    uint8_t* Bs = lds + 64 * 1024;                      // 64 KB
    float*   rp  = (float*)(lds + 128 * 1024);          // [8][32] row partials
    float*   cp8 = (float*)(lds + 128 * 1024 + 1024);   // [8][64] col partials

    const int tid  = threadIdx.x;
    const int wave = tid >> 6, lane = tid & 63;
    const int l15  = lane & 15, ks = lane >> 4;

    // Decode linear block id -> (bi, bj), bi <= bj. cum(bi) = bi*(129-bi)/2.
    const int t = blockIdx.x;
    int bi = (int)((129.0f - sqrtf(129.0f * 129.0f - 8.0f * (float)t)) * 0.5f);
    while (bi > 0 && bi * (129 - bi) / 2 > t) --bi;
    while ((bi + 1) * (129 - (bi + 1)) / 2 <= t) ++bi;
    const int bj = bi + (t - bi * (129 - bi) / 2);
    const bool diag = (bi == bj);

    const int wrow = (wave >> 1) * 32;   // 4 row-groups of 32
    const int wcol = (wave & 1) * 64;    // 2 col-halves of 64

    // ---- stage both full tiles, swizzled. Wave w owns rows [w*16, w*16+16).
    // CP16 #m covers rows w*16+2m, +1 (1024 B contiguous LDS). lane l ->
    // row +(l>>5), phys chunk l&31; source logical chunk = (l&31) ^ (row&7).
    const int lrow = lane >> 5;          // 0/1
    const int lch  = lane & 31;          // 16B chunk within 512B row
    const uint8_t* gA0 = zb + (size_t)(bi * 128 + wave * 16 + lrow) * D;
    const uint8_t* gB0 = zb + (size_t)(bj * 128 + wave * 16 + lrow) * D;
    uint8_t* lA = As + wave * 16 * 512;
    uint8_t* lB = Bs + wave * 16 * 512;
    #pragma unroll
    for (int m = 0; m < 8; ++m) {
        const int swm = (2 * m + lrow) & 7;
        const size_t so = (size_t)(2 * m) * D + (size_t)((lch ^ swm) * 16);
        ASYNC_CP16(gA0 + so, lA + 2 * m * 512);
        ASYNC_CP16(gB0 + so, lB + 2 * m * 512);
    }
    __syncthreads();   // the ONE drain: both tiles resident

    // ---- compute: 4 K-chunks of 128, no further barriers
    f32x4 acc[2][4] = {};
    const int sws = l15 & 7;
    #pragma unroll
    for (int kk = 0; kk < 4; ++kk) {
        const int p0 = (kk * 8 + ((2 * ks)     ^ sws)) * 16;
        const int p1 = (kk * 8 + ((2 * ks + 1) ^ sws)) * 16;
        i32x8 af[2], bg[4];
        #pragma unroll
        for (int f = 0; f < 2; ++f) {
            const uint8_t* base = As + (wrow + f * 16 + l15) * 512;
            i32x4 lo = *(const i32x4*)(base + p0);
            i32x4 hi = *(const i32x4*)(base + p1);
            af[f] = __builtin_shufflevector(lo, hi, 0, 1, 2, 3, 4, 5, 6, 7);
        }
        #pragma unroll
        for (int f = 0; f < 4; ++f) {
            const uint8_t* base = Bs + (wcol + f * 16 + l15) * 512;
            i32x4 lo = *(const i32x4*)(base + p0);
            i32x4 hi = *(const i32x4*)(base + p1);
            bg[f] = __builtin_shufflevector(lo, hi, 0, 1, 2, 3, 4, 5, 6, 7);
        }
        #pragma unroll
        for (int i = 0; i < 2; ++i)
            #pragma unroll
            for (int j = 0; j < 4; ++j)
                // fmt 0 = fp8 e4m3 for A and B; unit scales (e8m0 0x7F = 2^0)
                acc[i][j] = __builtin_amdgcn_mfma_scale_f32_16x16x128_f8f6f4(
                    af[i], bg[j], acc[i][j], 0, 0, 0, 0x7F, 0, 0x7F);
    }

    // Epilogue. C/D layout: row = ks*4 + r, col = l15 (within each 16x16).
    // e = exp(sim/T) = exp(2*acc). rp/cp8 live past the tile buffers (no
    // aliasing). Combine waves sharing each row-group / col-half, store once.
    float rowp[2][4] = {};
    #pragma unroll
    for (int j = 0; j < 4; ++j) {
        float cpj = 0.f;
        #pragma unroll
        for (int i = 0; i < 2; ++i)
            #pragma unroll
            for (int r = 0; r < 4; ++r) {
                float e = __expf(2.0f * acc[i][j][r]);
                rowp[i][r] += e;
                cpj += e;
            }
        if (!diag) {
            cpj += __shfl_xor(cpj, 16, 64);
            cpj += __shfl_xor(cpj, 32, 64);
            if (ks == 0) cp8[wave * 64 + j * 16 + l15] = cpj;
        }
    }
    #pragma unroll
    for (int i = 0; i < 2; ++i)
        #pragma unroll
        for (int r = 0; r < 4; ++r) {
            float e = rowp[i][r];
            e += __shfl_xor(e, 1, 64);
            e += __shfl_xor(e, 2, 64);
            e += __shfl_xor(e, 4, 64);
            e += __shfl_xor(e, 8, 64);
            if (l15 == 0) rp[wave * 32 + i * 16 + ks * 4 + r] = e;
        }
    __syncthreads();

    // rows m*32..+32 from waves {2m, 2m+1};
    // cols 0-63 from waves {0,2,4,6}, 64-127 from {1,3,5,7}.
    float* pA = partials + (size_t)(bi * NTILE + bj) * 128;
    float* pB = partials + (size_t)(bj * NTILE + bi) * 128;
    if (tid < 128) {
        const int mm = tid >> 5, rr = tid & 31;
        pA[tid] = rp[mm * 2 * 32 + rr] + rp[(mm * 2 + 1) * 32 + rr];
    } else if (tid < 256 && !diag) {
        const int c = tid - 128, h = c >> 6, cc = c & 63;
        pB[c] = cp8[h * 64 + cc] + cp8[(h + 2) * 64 + cc]
              + cp8[(h + 4) * 64 + cc] + cp8[(h + 6) * 64 + cc];
    }
}

// ---------------------------------------------------------------------------
// Kernel 3: per-tile-row reduction of partials + log terms + pos chunk,
// then one atomicAdd per block into out[0] (zeroed by normpos; stream order
// guarantees visibility; 64 adds total — negligible contention).
// ---------------------------------------------------------------------------
__global__ __launch_bounds__(256) void rowfin_kernel(
    const float* __restrict__ partials, const float* __restrict__ diagss,
    const float* __restrict__ pos, float* __restrict__ out)
{
    const int r  = blockIdx.x;          // tile-row 0..63
    const int ri = threadIdx.x & 127;   // row within tile
    const int ch = threadIdx.x >> 7;    // c-half 0/1
    const float* base = partials + (size_t)r * NTILE * 128 + ri;
    float s = 0.f;
    #pragma unroll
    for (int c = 0; c < 32; ++c)
        s += base[(size_t)(ch * 32 + c) * 128];
    __shared__ float half1[128];
    __shared__ float red[4];
    if (ch == 1) half1[ri] = s;
    __syncthreads();
    float lg = 0.f;
    if (ch == 0) {
        float rs = s + half1[ri];
        int row = r * 128 + ri;
        lg = __logf(rs - __expf(2.0f * diagss[row]));
    }
    if (threadIdx.x < 64)
        lg -= 2.0f * pos[r * 64 + threadIdx.x];
    #pragma unroll
    for (int off = 32; off; off >>= 1) lg += __shfl_xor(lg, off, 64);
    const int wave = threadIdx.x >> 6, lane = threadIdx.x & 63;
    if (lane == 0) red[wave] = lg;
    __syncthreads();
    if (threadIdx.x == 0)
        atomicAdd(out, (red[0] + red[1] + red[2] + red[3]) * (1.0f / 8192.0f));
}

// ---------------------------------------------------------------------------
extern "C" void kernel_launch(void* const* d_in, const int* in_sizes, int n_in,
                              void* d_out, int out_size, void* d_ws, size_t ws_size,
                              hipStream_t stream)
{
    const float* emb_i = (const float*)d_in[0];
    const float* emb_j = (const float*)d_in[1];

    // ws layout: zb fp8 [M][D] (4 MB) | partials f32[64][64][128] (2 MB)
    //            | diagss f32[M] | pos f32[N]   (~6.05 MB)
    uint8_t* zb = (uint8_t*)d_ws;
    float* partials = (float*)((char*)d_ws + (size_t)M * D);
    float* diagss   = partials + (size_t)NTILE * NTILE * 128;
    float* pos      = diagss + M;
    float* out      = (float*)d_out;

    normpos_kernel<<<N_ROWS / 4, 256, 0, stream>>>(emb_i, emb_j, zb, diagss,
                                                   pos, out);
    // dynamic LDS: 128 KB tiles + 1 KB rp + 2 KB cp8 = 134144 B
    simgemm_kernel<<<NBLK, 512, 134144, stream>>>(zb, partials);
    rowfin_kernel<<<NTILE, 256, 0, stream>>>(partials, diagss, pos, out);
}